// Round 1
// baseline (429.596 us; speedup 1.0000x reference)
//
#include <hip/hip_runtime.h>

#define SROW 132   // padded fp32 row stride for S (4r+8h mod32 -> <=2-way, b128-aligned)

typedef _Float16 half8 __attribute__((ext_vector_type(8)));
typedef float f32x4 __attribute__((ext_vector_type(4)));

// MFMA rewrite. Per block (one m): T = S * Sigma via fp16-split MFMA
// (S=hi+lo, Sigma=hi+lo, drop lo*lo: per-term err ~2^-24), then
// score[p] = -dot(T[p,:], S[p,:]) in fp32, softmax over p.
//
// Sigma staged in 32-row chunks, converted once per block into f16 hi/lo
// planes laid out EXACTLY as B-fragments: Bp[plane][tile][slot=h*16+r][j]
// where value = Sigma[kc+8h+j][16*tile+r]. Frag reads are lane-contiguous
// ds_read_b128 (conflict-free). Double-buffered, 1 barrier/chunk, chunk n+1
// global loads issued before chunk n's MFMA phase (latency hidden).

__global__ __launch_bounds__(256, 2)
void quadform_softmax(const float* __restrict__ color,
                      const float* __restrict__ mew,
                      const float* __restrict__ sigma,
                      float* __restrict__ out) {
  __shared__ __align__(16) float s_all[4 * 16 * SROW];        // 33792 B, per-wave S
  __shared__ __align__(16) _Float16 Bp[2][2][8][64][8];       // 32768 B: [buf][hi/lo][tile][slot][j]
  __shared__ float scores_lds[64];

  const int tid  = threadIdx.x;
  const int wv   = tid >> 6;
  const int lane = tid & 63;
  const int m    = blockIdx.x;

  float* sw = &s_all[wv * (16 * SROW)];
  const float* sg = sigma + (size_t)m * 16384;

  // ---- staging role for Sigma: this thread owns cols {c0, c0+64}, k-rows [8h,8h+8) of chunk ----
  const int c0 = tid & 63;
  const int h  = tid >> 6;

  // issue chunk-0 loads early (latency hides under S staging below)
  float pre[16];
#pragma unroll
  for (int i = 0; i < 8; ++i) pre[i]     = sg[(size_t)(8 * h + i) * 128 + c0];
#pragma unroll
  for (int i = 0; i < 8; ++i) pre[8 + i] = sg[(size_t)(8 * h + i) * 128 + c0 + 64];

  // ---- stage shifted rows [16wv,16wv+16) into this wave's private S segment ----
  {
    const int hh = lane >> 5;
    const int q  = lane & 31;
    const float4* c4 = reinterpret_cast<const float4*>(color + (size_t)m * 8192)
                       + (size_t)(16 * wv) * 32;
    const float4 mw = reinterpret_cast<const float4*>(mew + (size_t)m * 128)[q];
#pragma unroll
    for (int r = 0; r < 8; ++r) {
      const int row = hh + 2 * r;
      float4 v = c4[row * 32 + q];
      v.x -= mw.x; v.y -= mw.y; v.z -= mw.z; v.w -= mw.w;
      *reinterpret_cast<float4*>(&sw[row * SROW + 4 * q]) = v;
    }
  }

  // convert pre[] -> f16 hi/lo planes, write B-fragment slots
  auto stage_write = [&](int buf) {
    half8 hi0, lo0, hi1, lo1;
#pragma unroll
    for (int i = 0; i < 8; ++i) {
      float x = pre[i];
      _Float16 xh = (_Float16)x;
      hi0[i] = xh;
      lo0[i] = (_Float16)(x - (float)xh);
      float y = pre[8 + i];
      _Float16 yh = (_Float16)y;
      hi1[i] = yh;
      lo1[i] = (_Float16)(y - (float)yh);
    }
    const int t0 = c0 >> 4, r0 = c0 & 15, slot = h * 16 + r0;
    *reinterpret_cast<half8*>(&Bp[buf][0][t0    ][slot][0]) = hi0;
    *reinterpret_cast<half8*>(&Bp[buf][1][t0    ][slot][0]) = lo0;
    *reinterpret_cast<half8*>(&Bp[buf][0][t0 + 4][slot][0]) = hi1;
    *reinterpret_cast<half8*>(&Bp[buf][1][t0 + 4][slot][0]) = lo1;
  };

  stage_write(0);
  __syncthreads();

  f32x4 acc[8];
#pragma unroll
  for (int t = 0; t < 8; ++t) acc[t] = (f32x4){0.f, 0.f, 0.f, 0.f};

  const int hl = lane >> 4;   // k-group for fragments
  const int rl = lane & 15;   // A row within wave-tile / B col within tile

#pragma unroll 1
  for (int ch = 0; ch < 4; ++ch) {
    const int kc = ch * 32;
    // prefetch next chunk (T14: issue-early, consume-late)
    if (ch < 3) {
      const float* gn = sg + (size_t)(kc + 32) * 128;
#pragma unroll
      for (int i = 0; i < 8; ++i) pre[i]     = gn[(size_t)(8 * h + i) * 128 + c0];
#pragma unroll
      for (int i = 0; i < 8; ++i) pre[8 + i] = gn[(size_t)(8 * h + i) * 128 + c0 + 64];
    }

    // A fragment: S[16wv+rl][kc+8hl .. +8] -> f16 hi/lo
    half8 ah, al;
    {
      const float* sa = &sw[rl * SROW + kc + 8 * hl];
      float4 a0 = *reinterpret_cast<const float4*>(sa);
      float4 a1 = *reinterpret_cast<const float4*>(sa + 4);
      float av[8] = {a0.x, a0.y, a0.z, a0.w, a1.x, a1.y, a1.z, a1.w};
#pragma unroll
      for (int j = 0; j < 8; ++j) {
        _Float16 xh = (_Float16)av[j];
        ah[j] = xh;
        al[j] = (_Float16)(av[j] - (float)xh);
      }
    }

    const int buf = ch & 1;
#pragma unroll
    for (int t = 0; t < 8; ++t) {
      half8 bh = *reinterpret_cast<const half8*>(&Bp[buf][0][t][lane][0]);
      half8 bl = *reinterpret_cast<const half8*>(&Bp[buf][1][t][lane][0]);
      acc[t] = __builtin_amdgcn_mfma_f32_16x16x32_f16(ah, bh, acc[t], 0, 0, 0);
      acc[t] = __builtin_amdgcn_mfma_f32_16x16x32_f16(ah, bl, acc[t], 0, 0, 0);
      acc[t] = __builtin_amdgcn_mfma_f32_16x16x32_f16(al, bh, acc[t], 0, 0, 0);
    }

    if (ch < 3) stage_write(buf ^ 1);
    __syncthreads();
  }

  // ---- epilogue: score[p] = -sum_col T[p,col] * S[p,col] ----
  // D layout (verified): row = 4*(lane>>4)+reg, col = 16*tile + (lane&15)
  float part[4] = {0.f, 0.f, 0.f, 0.f};
#pragma unroll
  for (int t = 0; t < 8; ++t) {
#pragma unroll
    for (int r = 0; r < 4; ++r) {
      float sv = sw[(4 * hl + r) * SROW + 16 * t + rl];
      part[r] = fmaf(acc[t][r], sv, part[r]);
    }
  }
#pragma unroll
  for (int r = 0; r < 4; ++r) {
    part[r] += __shfl_xor(part[r], 1, 64);
    part[r] += __shfl_xor(part[r], 2, 64);
    part[r] += __shfl_xor(part[r], 4, 64);
    part[r] += __shfl_xor(part[r], 8, 64);
  }
  if (rl == 0) {
#pragma unroll
    for (int r = 0; r < 4; ++r)
      scores_lds[wv * 16 + 4 * hl + r] = -part[r];
  }
  __syncthreads();

  // ---- softmax over the 64 scores (single wave) ----
  if (tid < 64) {
    float sc = scores_lds[tid];
    float mx = sc;
#pragma unroll
    for (int off = 1; off < 64; off <<= 1) mx = fmaxf(mx, __shfl_xor(mx, off, 64));
    float e = __expf(sc - mx);
    float s = e;
#pragma unroll
    for (int off = 1; off < 64; off <<= 1) s += __shfl_xor(s, off, 64);
    out[(size_t)m * 64 + tid] = e / s;
  }
}

extern "C" void kernel_launch(void* const* d_in, const int* in_sizes, int n_in,
                              void* d_out, int out_size, void* d_ws, size_t ws_size,
                              hipStream_t stream) {
  const float* color = (const float*)d_in[0];   // (M,64,128) fp32
  const float* mew   = (const float*)d_in[1];   // (M,128)    fp32
  const float* sigma = (const float*)d_in[2];   // (M,128,128) fp32
  float* out = (float*)d_out;                   // (M,64) fp32
  const int M = in_sizes[1] / 128;
  quadform_softmax<<<M, 256, 0, stream>>>(color, mew, sigma, out);
}